// Round 11
// baseline (74.170 us; speedup 1.0000x reference)
//
#include <hip/hip_runtime.h>

#define HW 4096
#define LQ 8192
#define DD 256

typedef __bf16 bf16x8 __attribute__((ext_vector_type(8)));
typedef float  f32x4  __attribute__((ext_vector_type(4)));
typedef float  f32x2  __attribute__((ext_vector_type(2)));
typedef unsigned int u32;
typedef u32 u32x4 __attribute__((ext_vector_type(4)));
typedef u32 u32x2 __attribute__((ext_vector_type(2)));

__device__ __forceinline__ float bflo(u32 u) { return __uint_as_float(u << 16); }
__device__ __forceinline__ float bfhi(u32 u) { return __uint_as_float(u & 0xffff0000u); }

// async global->LDS, 16B per lane; LDS dest is wave-uniform base + lane*16
#define GLOAD16(g, l) __builtin_amdgcn_global_load_lds(                     \
    (__attribute__((address_space(1))) void*)(g),                          \
    (__attribute__((address_space(3))) void*)(l), 16, 0, 0)

// ---------------------------------------------------------------------------
// prep_all: z<8 -> src transpose (input [b][k][q] fp32 -> srcS bf16
// [row][k=256], rows 512B, XOR-swizzled 16B granules: byte ^= ((row&7)<<4)).
// z==8 -> weight transposes (WcatT [448][512B], WoutT [256][1024B]).
// ---------------------------------------------------------------------------
__global__ __launch_bounds__(256) void prep_all(const float* __restrict__ in_v,
                                                const float* __restrict__ in_i,
                                                const float* __restrict__ Wv,
                                                const float* __restrict__ Wo,
                                                const float* __restrict__ Wa,
                                                const float* __restrict__ Wout,
                                                char* __restrict__ srcS,
                                                char* __restrict__ WcatT,
                                                char* __restrict__ WoutT)
{
    __shared__ float tile[64][68];
    if (blockIdx.z < 8) {
        const int q0 = blockIdx.x * 64;
        const int k0 = blockIdx.y * 64;
        const int bz = blockIdx.z;                    // b*2 + l
        const float* src = ((bz & 1) ? in_i : in_v) + (size_t)(bz >> 1) * (DD * HW);
        const int t  = threadIdx.x;
        const int ql = (t & 15) * 4;
        const int kl = t >> 4;
#pragma unroll
        for (int rr = 0; rr < 4; ++rr) {
            const float4 v = *(const float4*)(src + (size_t)(k0 + kl + rr * 16) * HW + q0 + ql);
            *(float4*)&tile[kl + rr * 16][ql] = v;
        }
        __syncthreads();
        const int qrow = t >> 2;
        const int kc   = (t & 3) * 16;
        const int row  = (bz >> 1) * LQ + (bz & 1) * HW + q0 + qrow;
        bf16x8 p0, p1;
#pragma unroll
        for (int j = 0; j < 8; ++j) {
            p0[j] = (__bf16)tile[kc + j][qrow];
            p1[j] = (__bf16)tile[kc + 8 + j][qrow];
        }
        char* drow = srcS + (size_t)row * 512;
        const int sw   = (row & 7) << 4;
        const int base = k0 * 2 + kc * 2;
        *(bf16x8*)(drow + ((base)      ^ sw)) = p0;
        *(bf16x8*)(drow + ((base + 16) ^ sw)) = p1;
    } else {
        const int flat = blockIdx.y * 64 + blockIdx.x;
        if (flat >= 120) return;
        const int gi = flat * 256 + threadIdx.x;
        if (gi < 448 * 32) {
            const int row = gi >> 5;
            const int g   = gi & 31;
            const int k   = g * 8;
            const float* col; int stride;
            if (row < 256)      { col = Wv + row;         stride = 256; }
            else if (row < 384) { col = Wo + (row - 256); stride = 128; }
            else                { col = Wa + (row - 384); stride = 64;  }
            bf16x8 p;
#pragma unroll
            for (int j = 0; j < 8; ++j) p[j] = (__bf16)col[(size_t)(k + j) * stride];
            char* d = WcatT + (size_t)row * 512;
            *(bf16x8*)(d + ((g * 16) ^ ((row & 7) << 4))) = p;
        } else {
            const int gj = gi - 448 * 32;
            if (gj >= 256 * 64) return;
            const int c = gj >> 6;
            const int g = gj & 63;
            const int k = (g * 8) & 255;
            bf16x8 p;
#pragma unroll
            for (int j = 0; j < 8; ++j) p[j] = (__bf16)Wout[(size_t)(k + j) * 256 + c];
            char* d = WoutT + (size_t)c * 1024;
            *(bf16x8*)(d + ((g * 16) ^ ((c & 7) << 4))) = p;
        }
    }
}

// ---------------------------------------------------------------------------
// Fused projection GEMM (MFMA): C[32768 x 448] = srcS @ WcatT^T, K=256.
// y<3: BN=128 tiles (value 0..255, off 256..383); y==3: BN=64 (attn 384..447).
// value is written HEAD-MAJOR: [b][l][head][pix][32ch] so a bilinear corner's
// x-pair is contiguous 128B (one cache line) for the sampler.
// ---------------------------------------------------------------------------
template<int BN>
__device__ __forceinline__ void proj_tile(char* smem,
                                          const char* __restrict__ srcS,
                                          const char* __restrict__ WcatT,
                                          const float* __restrict__ b_value,
                                          const float* __restrict__ b_off,
                                          const float* __restrict__ b_attn,
                                          __bf16* __restrict__ valueH,
                                          __bf16* __restrict__ offB,
                                          __bf16* __restrict__ attnB,
                                          int M0, int N0)
{
    constexpr int NI = BN / 32;        // n-frags per wave (2 or 4)
    char* As = smem;                   // 128 rows x 128B
    char* Bs = smem + 16384;           // BN rows x 128B

    const int t = threadIdx.x;
    const int w = t >> 6;
    const int l = t & 63;
    const int lm = l & 15, lk = l >> 4;
    const int wave_m = (w >> 1) * 64;
    const int wave_n = (w & 1) * (BN / 2);

    f32x4 acc[4][NI] = {};

    const char* Ab = As + (wave_m + lm) * 128;
    const char* Bb = Bs + (wave_n + lm) * 128;
    const int go0 = (lk ^ (l & 7)) * 16;
    const int go1 = go0 ^ 64;

    for (int kt = 0; kt < 4; ++kt) {
        __syncthreads();
        const int kb = kt * 128;
#pragma unroll
        for (int c = 0; c < 4; ++c) {
            const char* g = srcS + (size_t)(M0 + w * 32 + c * 8 + (l >> 3)) * 512 + kb + (l & 7) * 16;
            GLOAD16(g, As + (w * 4 + c) * 1024);
        }
#pragma unroll
        for (int c = 0; c < NI; ++c) {
            const char* g = WcatT + (size_t)(N0 + w * (BN / 4) + c * 8 + (l >> 3)) * 512 + kb + (l & 7) * 16;
            GLOAD16(g, Bs + (w * NI + c) * 1024);
        }
        __syncthreads();

        bf16x8 af[4], bb[NI];
#pragma unroll
        for (int mi = 0; mi < 4; ++mi) af[mi] = *(const bf16x8*)(Ab + mi * 2048 + go0);
#pragma unroll
        for (int ni = 0; ni < NI; ++ni) bb[ni] = *(const bf16x8*)(Bb + ni * 2048 + go0);
#pragma unroll
        for (int mi = 0; mi < 4; ++mi)
#pragma unroll
            for (int ni = 0; ni < NI; ++ni)
                acc[mi][ni] = __builtin_amdgcn_mfma_f32_16x16x32_bf16(af[mi], bb[ni], acc[mi][ni], 0, 0, 0);
#pragma unroll
        for (int mi = 0; mi < 4; ++mi) af[mi] = *(const bf16x8*)(Ab + mi * 2048 + go1);
#pragma unroll
        for (int ni = 0; ni < NI; ++ni) bb[ni] = *(const bf16x8*)(Bb + ni * 2048 + go1);
#pragma unroll
        for (int mi = 0; mi < 4; ++mi)
#pragma unroll
            for (int ni = 0; ni < NI; ++ni)
                acc[mi][ni] = __builtin_amdgcn_mfma_f32_16x16x32_bf16(af[mi], bb[ni], acc[mi][ni], 0, 0, 0);
    }

    if (N0 < 256) {
        // head-major value write: idx = ((b2l*8 + head)*4096 + pix)*32 + d
#pragma unroll
        for (int ni = 0; ni < NI; ++ni) {
            const int cl = N0 + wave_n + ni * 16 + lm;
            const float bv = b_value[cl];
            const int hd  = cl >> 5;
            const int dch = cl & 31;
#pragma unroll
            for (int mi = 0; mi < 4; ++mi) {
                const int row = M0 + wave_m + mi * 16 + lk * 4;
                const int b2l = row >> 12;
                const int pix = row & 4095;
                __bf16* dst = valueH + ((size_t)((b2l * 8 + hd) * 4096 + pix)) * 32 + dch;
#pragma unroll
                for (int r = 0; r < 4; ++r)
                    dst[r * 32] = (__bf16)(acc[mi][ni][r] + bv);
            }
        }
    } else {
        __bf16* outp; const float* bias; int ncols, nbase;
        if (N0 < 384)  { outp = offB;  bias = b_off;  ncols = 128; nbase = 256; }
        else           { outp = attnB; bias = b_attn; ncols = 64;  nbase = 384; }
#pragma unroll
        for (int ni = 0; ni < NI; ++ni) {
            const int cl = N0 + wave_n + ni * 16 + lm - nbase;
            const float bv = bias[cl];
#pragma unroll
            for (int mi = 0; mi < 4; ++mi) {
                const int row = M0 + wave_m + mi * 16 + lk * 4;
#pragma unroll
                for (int r = 0; r < 4; ++r)
                    outp[(size_t)(row + r) * ncols + cl] = (__bf16)(acc[mi][ni][r] + bv);
            }
        }
    }
}

__global__ __launch_bounds__(256) void mfma_proj(const char* __restrict__ srcS,
                                                 const char* __restrict__ WcatT,
                                                 const float* __restrict__ b_value,
                                                 const float* __restrict__ b_off,
                                                 const float* __restrict__ b_attn,
                                                 __bf16* __restrict__ valueH,
                                                 __bf16* __restrict__ offB,
                                                 __bf16* __restrict__ attnB)
{
    __shared__ char smem[32768];
    const int M0 = blockIdx.x * 128;
    if (blockIdx.y < 3)
        proj_tile<128>(smem, srcS, WcatT, b_value, b_off, b_attn,
                       valueH, offB, attnB, M0, blockIdx.y * 128);
    else
        proj_tile<64>(smem, srcS, WcatT, b_value, b_off, b_attn,
                      valueH, offB, attnB, M0, 384);
}

// ---------------------------------------------------------------------------
// Sampling v9: v7 structure (2 q/wave, d8/lane, point-parallel weight calc,
// LDS slot table, XCD swizzle, setprio, packed f32x2 accumulate) over the
// head-major value layout: a point's x-corner pair is contiguous 128B, so
// each L1 line fill is fully consumed (2x fill efficiency).
// valueH addressing: b*4194304 + head*262144 + (l*32768 + pix)*64 + dl*16.
// ---------------------------------------------------------------------------
__global__ __launch_bounds__(256) void sample_kernel(const char* __restrict__ valueH,
                                                     const char* __restrict__ offB,
                                                     const char* __restrict__ attnB,
                                                     char* __restrict__ fusedS)
{
    __shared__ u32 wlds[4][128][8];               // [wave][slot=q2*64+head*8+pt][8]
    const int bid0 = blockIdx.x;
    const int bid  = ((bid0 & 7) << 9) | (bid0 >> 3);   // XCD swizzle (4096 = 8*512)
    const int w    = threadIdx.x >> 6;
    const int lane = threadIdx.x & 63;
    const int q2   = lane >> 5;
    const int sub  = lane & 31;
    const int head = sub >> 2;
    const int dl   = sub & 3;

    const int px   = bid & 15;                    // 16 x-patches of width 4
    const int py   = (bid >> 4) & 31;             // 32 y-patches of height 2
    const int half = (bid >> 9) & 1;
    const int b    = bid >> 10;
    const int x    = px * 4 + (w & 1) * 2 + q2;
    const int y    = py * 2 + (w >> 1);
    const int row  = b * LQ + half * HW + y * 64 + x;
    const float fx0 = (float)x;
    const float fy0 = (float)y;

    // --- Phase A: softmax (partial) + weights for this lane's 2 points ---
    const u32x4 lgp = *(const u32x4*)(attnB + (size_t)row * 128 + head * 16);
    float e8[8];
#pragma unroll
    for (int j = 0; j < 4; ++j) { e8[2 * j] = bflo(lgp[j]); e8[2 * j + 1] = bfhi(lgp[j]); }
    float mx = e8[0];
#pragma unroll
    for (int j = 1; j < 8; ++j) mx = fmaxf(mx, e8[j]);
    const int pt0 = dl * 2;
    const float ex0 = __expf(e8[pt0] - mx);
    const float ex1 = __expf(e8[pt0 + 1] - mx);
    float sp = ex0 + ex1;
    sp += __shfl_xor(sp, 1);
    sp += __shfl_xor(sp, 2);
    const float inv = 1.0f / sp;

    const u32x2 opk = *(const u32x2*)(offB + (size_t)row * 256 + head * 32 + dl * 8);
    u32* slotp = &wlds[w][q2 * 64 + head * 8 + pt0][0];
#pragma unroll
    for (int i = 0; i < 2; ++i) {
        const float ox = bflo(opk[i]);
        const float oy = bfhi(opk[i]);
        const float aw = (i ? ex1 : ex0) * inv;
        const float xx = fx0 + ox;
        const float yy = fy0 + oy;
        const float xf = floorf(xx), yf = floorf(yy);
        const int   xi = (int)xf,   yi = (int)yf;
        const float dx = xx - xf,   dy = yy - yf;
        const bool vx0 = (unsigned)xi       < 64u;
        const bool vx1 = (unsigned)(xi + 1) < 64u;
        const bool vy0 = (unsigned)yi       < 64u;
        const bool vy1 = (unsigned)(yi + 1) < 64u;
        f32x4 W;
        W[0] = (vx0 && vy0) ? aw * (1.f - dx) * (1.f - dy) : 0.f;
        W[1] = (vx1 && vy0) ? aw * dx * (1.f - dy)         : 0.f;
        W[2] = (vx0 && vy1) ? aw * (1.f - dx) * dy         : 0.f;
        W[3] = (vx1 && vy1) ? aw * dx * dy                 : 0.f;
        const int xc0 = min(max(xi, 0), 63);
        const int xc1 = min(max(xi + 1, 0), 63);
        const int yc0 = min(max(yi, 0), 63) << 6;
        const int yc1 = min(max(yi + 1, 0), 63) << 6;
        const int lvl = ((pt0 + i) >> 2) * 32768;  // level stride in 64B rows
        u32x4 S;                                   // byte offsets (pix*64)
        S[0] = (u32)(lvl + yc0 + xc0) << 6; S[1] = (u32)(lvl + yc0 + xc1) << 6;
        S[2] = (u32)(lvl + yc1 + xc0) << 6; S[3] = (u32)(lvl + yc1 + xc1) << 6;
        *(f32x4*)(slotp + i * 8)     = W;
        *(u32x4*)(slotp + i * 8 + 4) = S;
    }

    // --- Phase B: gather + packed accumulate (head-major layout) ---
    const char* vb = (const char*)valueH + (size_t)b * 4194304 + head * 262144 + dl * 16;
    const u32* slotb = &wlds[w][q2 * 64 + head * 8][0];
    f32x2 acc2[4] = {};
    __builtin_amdgcn_s_setprio(1);
#pragma unroll
    for (int pt = 0; pt < 8; ++pt) {
        const f32x4 W = *(const f32x4*)(slotb + pt * 8);
        const u32x4 S = *(const u32x4*)(slotb + pt * 8 + 4);
        const u32x4 g00 = *(const u32x4*)(vb + S[0]);
        const u32x4 g10 = *(const u32x4*)(vb + S[1]);
        const u32x4 g01 = *(const u32x4*)(vb + S[2]);
        const u32x4 g11 = *(const u32x4*)(vb + S[3]);
        const f32x2 w0 = {W[0], W[0]};
        const f32x2 w1 = {W[1], W[1]};
        const f32x2 w2 = {W[2], W[2]};
        const f32x2 w3 = {W[3], W[3]};
#pragma unroll
        for (int j = 0; j < 4; ++j) {
            const f32x2 v00 = {bflo(g00[j]), bfhi(g00[j])};
            const f32x2 v10 = {bflo(g10[j]), bfhi(g10[j])};
            const f32x2 v01 = {bflo(g01[j]), bfhi(g01[j])};
            const f32x2 v11 = {bflo(g11[j]), bfhi(g11[j])};
            acc2[j] += w0 * v00 + w1 * v10 + w2 * v01 + w3 * v11;
        }
    }
    __builtin_amdgcn_s_setprio(0);

    bf16x8 ov;
#pragma unroll
    for (int j = 0; j < 4; ++j) {
        ov[2 * j]     = (__bf16)acc2[j][0];
        ov[2 * j + 1] = (__bf16)acc2[j][1];
    }
    const int d8 = dl << 3;
    const int bo = (head * 64 + d8 * 2) ^ ((row & 7) << 4);
    *(bf16x8*)(fusedS + (size_t)row * 512 + bo) = ov;
}

// ---------------------------------------------------------------------------
// Output GEMM (MFMA): K=512 concat over the two halves (v+i sum absorbed);
// epilogue LDS-transpose -> coalesced fp32 stores along q.
// ---------------------------------------------------------------------------
__global__ __launch_bounds__(256) void mfma_out(const char* __restrict__ fusedS,
                                                const char* __restrict__ WoutT,
                                                const float* __restrict__ b_out,
                                                float* __restrict__ out)
{
    __shared__ char smem[24576];
    char* As = smem;
    char* Bs = smem + 16384;
    float* Tr = (float*)smem;

    const int M0 = blockIdx.x * 128;
    const int N0 = blockIdx.y * 64;
    const int bi = M0 >> 12;
    const int q0 = M0 & 4095;
    const int t = threadIdx.x;
    const int w = t >> 6;
    const int l = t & 63;
    const int lm = l & 15, lk = l >> 4;
    const int wave_m = (w >> 1) * 64;
    const int wave_n = (w & 1) * 32;

    f32x4 acc[4][2] = {};

    const char* Ab = As + (wave_m + lm) * 128;
    const char* Bb = Bs + (wave_n + lm) * 128;
    const int go0 = (lk ^ (l & 7)) * 16;
    const int go1 = go0 ^ 64;

    for (int kt = 0; kt < 8; ++kt) {
        __syncthreads();
        const int half = kt >> 2;
        const int kb   = (kt & 3) * 128;
#pragma unroll
        for (int c = 0; c < 4; ++c) {
            const char* g = fusedS + (size_t)(bi * LQ + half * HW + q0 + w * 32 + c * 8 + (l >> 3)) * 512
                          + kb + (l & 7) * 16;
            GLOAD16(g, As + (w * 4 + c) * 1024);
        }
#pragma unroll
        for (int c = 0; c < 2; ++c) {
            const char* g = WoutT + (size_t)(N0 + w * 16 + c * 8 + (l >> 3)) * 1024 + kt * 128 + (l & 7) * 16;
            GLOAD16(g, Bs + (w * 2 + c) * 1024);
        }
        __syncthreads();

        bf16x8 af[4], bb[2];
#pragma unroll
        for (int mi = 0; mi < 4; ++mi) af[mi] = *(const bf16x8*)(Ab + mi * 2048 + go0);
#pragma unroll
        for (int ni = 0; ni < 2; ++ni) bb[ni] = *(const bf16x8*)(Bb + ni * 2048 + go0);
#pragma unroll
        for (int mi = 0; mi < 4; ++mi)
#pragma unroll
            for (int ni = 0; ni < 2; ++ni)
                acc[mi][ni] = __builtin_amdgcn_mfma_f32_16x16x32_bf16(af[mi], bb[ni], acc[mi][ni], 0, 0, 0);
#pragma unroll
        for (int mi = 0; mi < 4; ++mi) af[mi] = *(const bf16x8*)(Ab + mi * 2048 + go1);
#pragma unroll
        for (int ni = 0; ni < 2; ++ni) bb[ni] = *(const bf16x8*)(Bb + ni * 2048 + go1);
#pragma unroll
        for (int mi = 0; mi < 4; ++mi)
#pragma unroll
            for (int ni = 0; ni < 2; ++ni)
                acc[mi][ni] = __builtin_amdgcn_mfma_f32_16x16x32_bf16(af[mi], bb[ni], acc[mi][ni], 0, 0, 0);
    }

    float bias2[2];
#pragma unroll
    for (int ni = 0; ni < 2; ++ni) bias2[ni] = 2.0f * b_out[N0 + wave_n + ni * 16 + lm];

#pragma unroll
    for (int h = 0; h < 2; ++h) {
        __syncthreads();
        if ((w >> 1) == h) {
#pragma unroll
            for (int mi = 0; mi < 4; ++mi)
#pragma unroll
                for (int ni = 0; ni < 2; ++ni)
#pragma unroll
                    for (int r = 0; r < 4; ++r)
                        Tr[(wave_n + ni * 16 + lm) * 68 + mi * 16 + lk * 4 + r] = acc[mi][ni][r] + bias2[ni];
        }
        __syncthreads();
        const int c  = t >> 2;
        const int qo = (t & 3) * 16;
        float* dst = out + ((size_t)(bi * DD + N0 + c)) * HW + q0 + h * 64 + qo;
        const float* sp = Tr + c * 68 + qo;
#pragma unroll
        for (int j = 0; j < 4; ++j)
            *(f32x4*)(dst + j * 4) = *(const f32x4*)(sp + j * 4);
    }
}

extern "C" void kernel_launch(void* const* d_in, const int* in_sizes, int n_in,
                              void* d_out, int out_size, void* d_ws, size_t ws_size,
                              hipStream_t stream) {
    const float* in_v    = (const float*)d_in[0];
    const float* in_i    = (const float*)d_in[1];
    const float* W_value = (const float*)d_in[2];
    const float* b_value = (const float*)d_in[3];
    const float* W_off   = (const float*)d_in[4];
    const float* b_off   = (const float*)d_in[5];
    const float* W_attn  = (const float*)d_in[6];
    const float* b_attn  = (const float*)d_in[7];
    const float* W_out   = (const float*)d_in[8];
    const float* b_out   = (const float*)d_in[9];
    float* out = (float*)d_out;

    char* ws = (char*)d_ws;
    __bf16* valueH = (__bf16*)(ws);                 // 16.78 MB [b][l][head][4096][64B]
    __bf16* offB   = (__bf16*)(ws + 16777216);      //  8.39 MB [32768][256B]
    __bf16* attnB  = (__bf16*)(ws + 25165824);      //  4.19 MB [32768][128B]
    char*   srcS   = ws + 29360128;                 // 16.78 MB [32768][512B]
    char*   fusedS = ws + 46137344;                 // 16.78 MB [32768][512B]
    char*   WcatT  = ws + 62914560;                 // 229 KB
    char*   WoutT  = ws + 63143936;                 // 256 KB

    prep_all<<<dim3(64, 4, 9), 256, 0, stream>>>(in_v, in_i, W_value, W_off, W_attn, W_out,
                                                 srcS, WcatT, WoutT);
    mfma_proj<<<dim3(256, 4), 256, 0, stream>>>(srcS, WcatT, b_value, b_off, b_attn,
                                                valueH, offB, attnB);
    sample_kernel<<<dim3(4096), 256, 0, stream>>>((const char*)valueH, (const char*)offB,
                                                  (const char*)attnB, fusedS);
    mfma_out<<<dim3(128, 4), 256, 0, stream>>>(fusedS, WoutT, b_out, out);
}

// Round 12
// 72.795 us; speedup vs baseline: 1.0189x; 1.0189x over previous
//
#include <hip/hip_runtime.h>

#define HW 4096
#define LQ 8192
#define DD 256

typedef __bf16 bf16x8 __attribute__((ext_vector_type(8)));
typedef float  f32x4  __attribute__((ext_vector_type(4)));
typedef float  f32x2  __attribute__((ext_vector_type(2)));
typedef unsigned int u32;
typedef u32 u32x4 __attribute__((ext_vector_type(4)));
typedef u32 u32x2 __attribute__((ext_vector_type(2)));

__device__ __forceinline__ float bflo(u32 u) { return __uint_as_float(u << 16); }
__device__ __forceinline__ float bfhi(u32 u) { return __uint_as_float(u & 0xffff0000u); }

// async global->LDS, 16B per lane; LDS dest is wave-uniform base + lane*16
#define GLOAD16(g, l) __builtin_amdgcn_global_load_lds(                     \
    (__attribute__((address_space(1))) void*)(g),                          \
    (__attribute__((address_space(3))) void*)(l), 16, 0, 0)

// ---------------------------------------------------------------------------
// prep_all: z<8 -> src transpose (input [b][k][q] fp32 -> srcS bf16
// [row][k=256], rows 512B, XOR-swizzled 16B granules: byte ^= ((row&7)<<4)).
// z==8 -> weight transposes (WcatT [448][512B], WoutT [256][1024B]).
// ---------------------------------------------------------------------------
__global__ __launch_bounds__(256) void prep_all(const float* __restrict__ in_v,
                                                const float* __restrict__ in_i,
                                                const float* __restrict__ Wv,
                                                const float* __restrict__ Wo,
                                                const float* __restrict__ Wa,
                                                const float* __restrict__ Wout,
                                                char* __restrict__ srcS,
                                                char* __restrict__ WcatT,
                                                char* __restrict__ WoutT)
{
    __shared__ float tile[64][68];
    if (blockIdx.z < 8) {
        const int q0 = blockIdx.x * 64;
        const int k0 = blockIdx.y * 64;
        const int bz = blockIdx.z;                    // b*2 + l
        const float* src = ((bz & 1) ? in_i : in_v) + (size_t)(bz >> 1) * (DD * HW);
        const int t  = threadIdx.x;
        const int ql = (t & 15) * 4;
        const int kl = t >> 4;
#pragma unroll
        for (int rr = 0; rr < 4; ++rr) {
            const float4 v = *(const float4*)(src + (size_t)(k0 + kl + rr * 16) * HW + q0 + ql);
            *(float4*)&tile[kl + rr * 16][ql] = v;
        }
        __syncthreads();
        const int qrow = t >> 2;
        const int kc   = (t & 3) * 16;
        const int row  = (bz >> 1) * LQ + (bz & 1) * HW + q0 + qrow;
        bf16x8 p0, p1;
#pragma unroll
        for (int j = 0; j < 8; ++j) {
            p0[j] = (__bf16)tile[kc + j][qrow];
            p1[j] = (__bf16)tile[kc + 8 + j][qrow];
        }
        char* drow = srcS + (size_t)row * 512;
        const int sw   = (row & 7) << 4;
        const int base = k0 * 2 + kc * 2;
        *(bf16x8*)(drow + ((base)      ^ sw)) = p0;
        *(bf16x8*)(drow + ((base + 16) ^ sw)) = p1;
    } else {
        const int flat = blockIdx.y * 64 + blockIdx.x;
        if (flat >= 120) return;
        const int gi = flat * 256 + threadIdx.x;
        if (gi < 448 * 32) {
            const int row = gi >> 5;
            const int g   = gi & 31;
            const int k   = g * 8;
            const float* col; int stride;
            if (row < 256)      { col = Wv + row;         stride = 256; }
            else if (row < 384) { col = Wo + (row - 256); stride = 128; }
            else                { col = Wa + (row - 384); stride = 64;  }
            bf16x8 p;
#pragma unroll
            for (int j = 0; j < 8; ++j) p[j] = (__bf16)col[(size_t)(k + j) * stride];
            char* d = WcatT + (size_t)row * 512;
            *(bf16x8*)(d + ((g * 16) ^ ((row & 7) << 4))) = p;
        } else {
            const int gj = gi - 448 * 32;
            if (gj >= 256 * 64) return;
            const int c = gj >> 6;
            const int g = gj & 63;
            const int k = (g * 8) & 255;
            bf16x8 p;
#pragma unroll
            for (int j = 0; j < 8; ++j) p[j] = (__bf16)Wout[(size_t)(k + j) * 256 + c];
            char* d = WoutT + (size_t)c * 1024;
            *(bf16x8*)(d + ((g * 16) ^ ((c & 7) << 4))) = p;
        }
    }
}

// ---------------------------------------------------------------------------
// Fused projection GEMM (MFMA): C[32768 x 448] = srcS @ WcatT^T, K=256.
// y<3: BN=128 tiles (value 0..255, off 256..383); y==3: BN=64 (attn 384..447).
// ---------------------------------------------------------------------------
template<int BN>
__device__ __forceinline__ void proj_tile(char* smem,
                                          const char* __restrict__ srcS,
                                          const char* __restrict__ WcatT,
                                          const float* __restrict__ b_value,
                                          const float* __restrict__ b_off,
                                          const float* __restrict__ b_attn,
                                          __bf16* __restrict__ valueB,
                                          __bf16* __restrict__ offB,
                                          __bf16* __restrict__ attnB,
                                          int M0, int N0)
{
    constexpr int NI = BN / 32;        // n-frags per wave (2 or 4)
    char* As = smem;                   // 128 rows x 128B
    char* Bs = smem + 16384;           // BN rows x 128B

    const int t = threadIdx.x;
    const int w = t >> 6;
    const int l = t & 63;
    const int lm = l & 15, lk = l >> 4;
    const int wave_m = (w >> 1) * 64;
    const int wave_n = (w & 1) * (BN / 2);

    f32x4 acc[4][NI] = {};

    const char* Ab = As + (wave_m + lm) * 128;
    const char* Bb = Bs + (wave_n + lm) * 128;
    const int go0 = (lk ^ (l & 7)) * 16;
    const int go1 = go0 ^ 64;

    for (int kt = 0; kt < 4; ++kt) {
        __syncthreads();
        const int kb = kt * 128;
#pragma unroll
        for (int c = 0; c < 4; ++c) {
            const char* g = srcS + (size_t)(M0 + w * 32 + c * 8 + (l >> 3)) * 512 + kb + (l & 7) * 16;
            GLOAD16(g, As + (w * 4 + c) * 1024);
        }
#pragma unroll
        for (int c = 0; c < NI; ++c) {
            const char* g = WcatT + (size_t)(N0 + w * (BN / 4) + c * 8 + (l >> 3)) * 512 + kb + (l & 7) * 16;
            GLOAD16(g, Bs + (w * NI + c) * 1024);
        }
        __syncthreads();

        bf16x8 af[4], bb[NI];
#pragma unroll
        for (int mi = 0; mi < 4; ++mi) af[mi] = *(const bf16x8*)(Ab + mi * 2048 + go0);
#pragma unroll
        for (int ni = 0; ni < NI; ++ni) bb[ni] = *(const bf16x8*)(Bb + ni * 2048 + go0);
#pragma unroll
        for (int mi = 0; mi < 4; ++mi)
#pragma unroll
            for (int ni = 0; ni < NI; ++ni)
                acc[mi][ni] = __builtin_amdgcn_mfma_f32_16x16x32_bf16(af[mi], bb[ni], acc[mi][ni], 0, 0, 0);
#pragma unroll
        for (int mi = 0; mi < 4; ++mi) af[mi] = *(const bf16x8*)(Ab + mi * 2048 + go1);
#pragma unroll
        for (int ni = 0; ni < NI; ++ni) bb[ni] = *(const bf16x8*)(Bb + ni * 2048 + go1);
#pragma unroll
        for (int mi = 0; mi < 4; ++mi)
#pragma unroll
            for (int ni = 0; ni < NI; ++ni)
                acc[mi][ni] = __builtin_amdgcn_mfma_f32_16x16x32_bf16(af[mi], bb[ni], acc[mi][ni], 0, 0, 0);
    }

    // region is block-uniform by construction
    __bf16* outp; const float* bias; int ncols, nbase;
    if (N0 < 256)       { outp = valueB; bias = b_value; ncols = 256; nbase = 0;   }
    else if (N0 < 384)  { outp = offB;   bias = b_off;   ncols = 128; nbase = 256; }
    else                { outp = attnB;  bias = b_attn;  ncols = 64;  nbase = 384; }

#pragma unroll
    for (int ni = 0; ni < NI; ++ni) {
        const int cl = N0 + wave_n + ni * 16 + lm - nbase;
        const float bv = bias[cl];
#pragma unroll
        for (int mi = 0; mi < 4; ++mi) {
            const int row = M0 + wave_m + mi * 16 + lk * 4;
#pragma unroll
            for (int r = 0; r < 4; ++r)
                outp[(size_t)(row + r) * ncols + cl] = (__bf16)(acc[mi][ni][r] + bv);
        }
    }
}

__global__ __launch_bounds__(256) void mfma_proj(const char* __restrict__ srcS,
                                                 const char* __restrict__ WcatT,
                                                 const float* __restrict__ b_value,
                                                 const float* __restrict__ b_off,
                                                 const float* __restrict__ b_attn,
                                                 __bf16* __restrict__ valueB,
                                                 __bf16* __restrict__ offB,
                                                 __bf16* __restrict__ attnB)
{
    __shared__ char smem[32768];
    const int M0 = blockIdx.x * 128;
    if (blockIdx.y < 3)
        proj_tile<128>(smem, srcS, WcatT, b_value, b_off, b_attn,
                       valueB, offB, attnB, M0, blockIdx.y * 128);
    else
        proj_tile<64>(smem, srcS, WcatT, b_value, b_off, b_attn,
                      valueB, offB, attnB, M0, 384);
}

// ---------------------------------------------------------------------------
// Sampling v7 (best verified): 2 q/wave, d8/lane, point-parallel weight calc
// via per-wave LDS slot table, XCD swizzle, setprio, packed f32x2 accumulate,
// pre-shifted byte offsets.
// ---------------------------------------------------------------------------
__global__ __launch_bounds__(256) void sample_kernel(const char* __restrict__ valueB,
                                                     const char* __restrict__ offB,
                                                     const char* __restrict__ attnB,
                                                     char* __restrict__ fusedS)
{
    __shared__ u32 wlds[4][128][8];               // [wave][slot=q2*64+head*8+pt][8]
    const int bid0 = blockIdx.x;
    const int bid  = ((bid0 & 7) << 9) | (bid0 >> 3);   // XCD swizzle (4096 = 8*512)
    const int w    = threadIdx.x >> 6;
    const int lane = threadIdx.x & 63;
    const int q2   = lane >> 5;
    const int sub  = lane & 31;
    const int head = sub >> 2;
    const int dl   = sub & 3;

    const int px   = bid & 15;                    // 16 x-patches of width 4
    const int py   = (bid >> 4) & 31;             // 32 y-patches of height 2
    const int half = (bid >> 9) & 1;
    const int b    = bid >> 10;
    const int x    = px * 4 + (w & 1) * 2 + q2;
    const int y    = py * 2 + (w >> 1);
    const int row  = b * LQ + half * HW + y * 64 + x;
    const float fx0 = (float)x;
    const float fy0 = (float)y;

    // --- Phase A: softmax (partial) + weights for this lane's 2 points ---
    const u32x4 lgp = *(const u32x4*)(attnB + (size_t)row * 128 + head * 16);
    float e8[8];
#pragma unroll
    for (int j = 0; j < 4; ++j) { e8[2 * j] = bflo(lgp[j]); e8[2 * j + 1] = bfhi(lgp[j]); }
    float mx = e8[0];
#pragma unroll
    for (int j = 1; j < 8; ++j) mx = fmaxf(mx, e8[j]);
    const int pt0 = dl * 2;
    const float ex0 = __expf(e8[pt0] - mx);
    const float ex1 = __expf(e8[pt0 + 1] - mx);
    float sp = ex0 + ex1;
    sp += __shfl_xor(sp, 1);
    sp += __shfl_xor(sp, 2);
    const float inv = 1.0f / sp;

    const u32x2 opk = *(const u32x2*)(offB + (size_t)row * 256 + head * 32 + dl * 8);
    u32* slotp = &wlds[w][q2 * 64 + head * 8 + pt0][0];
#pragma unroll
    for (int i = 0; i < 2; ++i) {
        const float ox = bflo(opk[i]);
        const float oy = bfhi(opk[i]);
        const float aw = (i ? ex1 : ex0) * inv;
        const float xx = fx0 + ox;
        const float yy = fy0 + oy;
        const float xf = floorf(xx), yf = floorf(yy);
        const int   xi = (int)xf,   yi = (int)yf;
        const float dx = xx - xf,   dy = yy - yf;
        const bool vx0 = (unsigned)xi       < 64u;
        const bool vx1 = (unsigned)(xi + 1) < 64u;
        const bool vy0 = (unsigned)yi       < 64u;
        const bool vy1 = (unsigned)(yi + 1) < 64u;
        f32x4 W;
        W[0] = (vx0 && vy0) ? aw * (1.f - dx) * (1.f - dy) : 0.f;
        W[1] = (vx1 && vy0) ? aw * dx * (1.f - dy)         : 0.f;
        W[2] = (vx0 && vy1) ? aw * (1.f - dx) * dy         : 0.f;
        W[3] = (vx1 && vy1) ? aw * dx * dy                 : 0.f;
        const int xc0 = min(max(xi, 0), 63);
        const int xc1 = min(max(xi + 1, 0), 63);
        const int yc0 = min(max(yi, 0), 63) << 6;
        const int yc1 = min(max(yi + 1, 0), 63) << 6;
        const int lvl = ((pt0 + i) >> 2) * HW;    // level offset in rows
        u32x4 S;                                   // byte offsets, pre-shifted
        S[0] = (u32)(lvl + yc0 + xc0) << 9; S[1] = (u32)(lvl + yc0 + xc1) << 9;
        S[2] = (u32)(lvl + yc1 + xc0) << 9; S[3] = (u32)(lvl + yc1 + xc1) << 9;
        *(f32x4*)(slotp + i * 8)     = W;
        *(u32x4*)(slotp + i * 8 + 4) = S;
    }

    // --- Phase B: gather + packed accumulate ---
    const int d8 = dl << 3;
    const char* vb = valueB + (((size_t)(b * LQ)) << 9) + head * 64 + d8 * 2;
    const u32* slotb = &wlds[w][q2 * 64 + head * 8][0];
    f32x2 acc2[4] = {};
    __builtin_amdgcn_s_setprio(1);
#pragma unroll
    for (int pt = 0; pt < 8; ++pt) {
        const f32x4 W = *(const f32x4*)(slotb + pt * 8);
        const u32x4 S = *(const u32x4*)(slotb + pt * 8 + 4);
        const u32x4 g00 = *(const u32x4*)(vb + S[0]);
        const u32x4 g10 = *(const u32x4*)(vb + S[1]);
        const u32x4 g01 = *(const u32x4*)(vb + S[2]);
        const u32x4 g11 = *(const u32x4*)(vb + S[3]);
        const f32x2 w0 = {W[0], W[0]};
        const f32x2 w1 = {W[1], W[1]};
        const f32x2 w2 = {W[2], W[2]};
        const f32x2 w3 = {W[3], W[3]};
#pragma unroll
        for (int j = 0; j < 4; ++j) {
            const f32x2 v00 = {bflo(g00[j]), bfhi(g00[j])};
            const f32x2 v10 = {bflo(g10[j]), bfhi(g10[j])};
            const f32x2 v01 = {bflo(g01[j]), bfhi(g01[j])};
            const f32x2 v11 = {bflo(g11[j]), bfhi(g11[j])};
            acc2[j] += w0 * v00 + w1 * v10 + w2 * v01 + w3 * v11;
        }
    }
    __builtin_amdgcn_s_setprio(0);

    bf16x8 ov;
#pragma unroll
    for (int j = 0; j < 4; ++j) {
        ov[2 * j]     = (__bf16)acc2[j][0];
        ov[2 * j + 1] = (__bf16)acc2[j][1];
    }
    const int bo = (head * 64 + d8 * 2) ^ ((row & 7) << 4);
    *(bf16x8*)(fusedS + (size_t)row * 512 + bo) = ov;
}

// ---------------------------------------------------------------------------
// Output GEMM (MFMA): K=512 concat over the two halves (v+i sum absorbed);
// epilogue LDS-transpose -> coalesced fp32 stores along q.
// ---------------------------------------------------------------------------
__global__ __launch_bounds__(256) void mfma_out(const char* __restrict__ fusedS,
                                                const char* __restrict__ WoutT,
                                                const float* __restrict__ b_out,
                                                float* __restrict__ out)
{
    __shared__ char smem[24576];
    char* As = smem;
    char* Bs = smem + 16384;
    float* Tr = (float*)smem;

    const int M0 = blockIdx.x * 128;
    const int N0 = blockIdx.y * 64;
    const int bi = M0 >> 12;
    const int q0 = M0 & 4095;
    const int t = threadIdx.x;
    const int w = t >> 6;
    const int l = t & 63;
    const int lm = l & 15, lk = l >> 4;
    const int wave_m = (w >> 1) * 64;
    const int wave_n = (w & 1) * 32;

    f32x4 acc[4][2] = {};

    const char* Ab = As + (wave_m + lm) * 128;
    const char* Bb = Bs + (wave_n + lm) * 128;
    const int go0 = (lk ^ (l & 7)) * 16;
    const int go1 = go0 ^ 64;

    for (int kt = 0; kt < 8; ++kt) {
        __syncthreads();
        const int half = kt >> 2;
        const int kb   = (kt & 3) * 128;
#pragma unroll
        for (int c = 0; c < 4; ++c) {
            const char* g = fusedS + (size_t)(bi * LQ + half * HW + q0 + w * 32 + c * 8 + (l >> 3)) * 512
                          + kb + (l & 7) * 16;
            GLOAD16(g, As + (w * 4 + c) * 1024);
        }
#pragma unroll
        for (int c = 0; c < 2; ++c) {
            const char* g = WoutT + (size_t)(N0 + w * 16 + c * 8 + (l >> 3)) * 1024 + kt * 128 + (l & 7) * 16;
            GLOAD16(g, Bs + (w * 2 + c) * 1024);
        }
        __syncthreads();

        bf16x8 af[4], bb[2];
#pragma unroll
        for (int mi = 0; mi < 4; ++mi) af[mi] = *(const bf16x8*)(Ab + mi * 2048 + go0);
#pragma unroll
        for (int ni = 0; ni < 2; ++ni) bb[ni] = *(const bf16x8*)(Bb + ni * 2048 + go0);
#pragma unroll
        for (int mi = 0; mi < 4; ++mi)
#pragma unroll
            for (int ni = 0; ni < 2; ++ni)
                acc[mi][ni] = __builtin_amdgcn_mfma_f32_16x16x32_bf16(af[mi], bb[ni], acc[mi][ni], 0, 0, 0);
#pragma unroll
        for (int mi = 0; mi < 4; ++mi) af[mi] = *(const bf16x8*)(Ab + mi * 2048 + go1);
#pragma unroll
        for (int ni = 0; ni < 2; ++ni) bb[ni] = *(const bf16x8*)(Bb + ni * 2048 + go1);
#pragma unroll
        for (int mi = 0; mi < 4; ++mi)
#pragma unroll
            for (int ni = 0; ni < 2; ++ni)
                acc[mi][ni] = __builtin_amdgcn_mfma_f32_16x16x32_bf16(af[mi], bb[ni], acc[mi][ni], 0, 0, 0);
    }

    float bias2[2];
#pragma unroll
    for (int ni = 0; ni < 2; ++ni) bias2[ni] = 2.0f * b_out[N0 + wave_n + ni * 16 + lm];

#pragma unroll
    for (int h = 0; h < 2; ++h) {
        __syncthreads();
        if ((w >> 1) == h) {
#pragma unroll
            for (int mi = 0; mi < 4; ++mi)
#pragma unroll
                for (int ni = 0; ni < 2; ++ni)
#pragma unroll
                    for (int r = 0; r < 4; ++r)
                        Tr[(wave_n + ni * 16 + lm) * 68 + mi * 16 + lk * 4 + r] = acc[mi][ni][r] + bias2[ni];
        }
        __syncthreads();
        const int c  = t >> 2;
        const int qo = (t & 3) * 16;
        float* dst = out + ((size_t)(bi * DD + N0 + c)) * HW + q0 + h * 64 + qo;
        const float* sp = Tr + c * 68 + qo;
#pragma unroll
        for (int j = 0; j < 4; ++j)
            *(f32x4*)(dst + j * 4) = *(const f32x4*)(sp + j * 4);
    }
}

extern "C" void kernel_launch(void* const* d_in, const int* in_sizes, int n_in,
                              void* d_out, int out_size, void* d_ws, size_t ws_size,
                              hipStream_t stream) {
    const float* in_v    = (const float*)d_in[0];
    const float* in_i    = (const float*)d_in[1];
    const float* W_value = (const float*)d_in[2];
    const float* b_value = (const float*)d_in[3];
    const float* W_off   = (const float*)d_in[4];
    const float* b_off   = (const float*)d_in[5];
    const float* W_attn  = (const float*)d_in[6];
    const float* b_attn  = (const float*)d_in[7];
    const float* W_out   = (const float*)d_in[8];
    const float* b_out   = (const float*)d_in[9];
    float* out = (float*)d_out;

    char* ws = (char*)d_ws;
    __bf16* valueB = (__bf16*)(ws);                 // 16.78 MB [32768][512B]
    __bf16* offB   = (__bf16*)(ws + 16777216);      //  8.39 MB [32768][256B]
    __bf16* attnB  = (__bf16*)(ws + 25165824);      //  4.19 MB [32768][128B]
    char*   srcS   = ws + 29360128;                 // 16.78 MB [32768][512B]
    char*   fusedS = ws + 46137344;                 // 16.78 MB [32768][512B]
    char*   WcatT  = ws + 62914560;                 // 229 KB
    char*   WoutT  = ws + 63143936;                 // 256 KB

    prep_all<<<dim3(64, 4, 9), 256, 0, stream>>>(in_v, in_i, W_value, W_off, W_attn, W_out,
                                                 srcS, WcatT, WoutT);
    mfma_proj<<<dim3(256, 4), 256, 0, stream>>>(srcS, WcatT, b_value, b_off, b_attn,
                                                valueB, offB, attnB);
    sample_kernel<<<dim3(4096), 256, 0, stream>>>((const char*)valueB, (const char*)offB,
                                                  (const char*)attnB, fusedS);
    mfma_out<<<dim3(128, 4), 256, 0, stream>>>(fusedS, WoutT, b_out, out);
}